// Round 6
// baseline (101.498 us; speedup 1.0000x reference)
//
#include <hip/hip_runtime.h>

#define NN 1024
#define DG 8
#define FO 64
#define FI 128
#define LALPHA 0.2f
#define BR 16        // output rows per fused block
#define SBS 257      // Sb row stride (u32 words), odd -> dense sweeps conflict-free
#define MTS 1032     // Mt row stride (ushorts); 516 words = 4 mod 32 (b128-clean)

typedef __attribute__((ext_vector_type(8))) short bf16x8;
typedef __attribute__((ext_vector_type(4))) float f32x4;

static __device__ __forceinline__ unsigned short f2bf(float x) {
  union { float f; unsigned u; } v; v.f = x;
  unsigned r = v.u + 0x7FFFu + ((v.u >> 16) & 1u);  // round-to-nearest-even
  return (unsigned short)(r >> 16);
}
static __device__ __forceinline__ float bf2f(unsigned short h) {
  union { unsigned u; float f; } v; v.u = ((unsigned)h) << 16;
  return v.f;
}

// ---------------------------------------------------------------------------
// K1 (prep): dedupe edges (t<16) + h = atom@W via bf16 hi/lo MFMA, fragments
// straight from global; outputs hT[g][f][node] (bf16 transposed), srcv/dstv.
// (unchanged from round 5 — isolates this round's k_fused change)
// ---------------------------------------------------------------------------
__global__ __launch_bounds__(256) void k_prep(const float* __restrict__ atoms,
                                              const float* __restrict__ W,
                                              const float* __restrict__ a,
                                              const int* __restrict__ edges,
                                              int* __restrict__ uniq,
                                              ushort* __restrict__ hT,
                                              float* __restrict__ srcv,
                                              float* __restrict__ dstv) {
  __shared__ float sp[16], dp[16];
  const int t = threadIdx.x, b = blockIdx.x;
  const int g = b >> 6;
  const int rbase = b * 16;

  if (t < 16) {
    sp[t] = 0.f; dp[t] = 0.f;
    const int rr = rbase + t;
    int e[DG];
#pragma unroll
    for (int s = 0; s < DG; s++) e[s] = edges[rr * DG + s];
#pragma unroll
    for (int s = 0; s < DG; s++) {
      int v = e[s];
      bool dup = false;
#pragma unroll
      for (int q = 0; q < DG; q++)
        if (q < s && e[q] == v) dup = true;
      uniq[rr * DG + s] = dup ? -1 : v;
    }
  }

  const int w = t >> 6, lane = t & 63, quad = lane >> 4, l16 = lane & 15;
  const float* __restrict__ Ar = atoms + (size_t)(rbase + l16) * FI;
  const float* __restrict__ Wc = W + w * 16 + l16;
  f32x4 acc = {0.f, 0.f, 0.f, 0.f};
#pragma unroll
  for (int kc = 0; kc < 4; kc++) {
    const int k0 = kc * 32 + quad * 8;
    float4 a0 = *(const float4*)(Ar + k0);
    float4 a1 = *(const float4*)(Ar + k0 + 4);
    float av[8] = {a0.x, a0.y, a0.z, a0.w, a1.x, a1.y, a1.z, a1.w};
    float wv[8];
#pragma unroll
    for (int e = 0; e < 8; e++) wv[e] = Wc[(k0 + e) * FO];
    bf16x8 ahi, alo, bhi, blo;
#pragma unroll
    for (int e = 0; e < 8; e++) {
      ushort h = f2bf(av[e]);
      ahi[e] = (short)h;
      alo[e] = (short)f2bf(av[e] - bf2f(h));
      ushort g2 = f2bf(wv[e]);
      bhi[e] = (short)g2;
      blo[e] = (short)f2bf(wv[e] - bf2f(g2));
    }
    acc = __builtin_amdgcn_mfma_f32_16x16x32_bf16(ahi, bhi, acc, 0, 0, 0);
    acc = __builtin_amdgcn_mfma_f32_16x16x32_bf16(ahi, blo, acc, 0, 0, 0);
    acc = __builtin_amdgcn_mfma_f32_16x16x32_bf16(alo, bhi, acc, 0, 0, 0);
  }

  const int f = w * 16 + l16;
  const float as_ = a[f], ad_ = a[FO + f];
  float ps[4], pd[4];
#pragma unroll
  for (int r = 0; r < 4; r++) {
    float v = acc[r];
    int rb = rbase + quad * 4 + r;
    hT[((size_t)g * FO + f) * NN + (rb & (NN - 1))] = f2bf(v);
    ps[r] = v * as_;
    pd[r] = v * ad_;
  }
#pragma unroll
  for (int off = 1; off < 16; off <<= 1)
#pragma unroll
    for (int r = 0; r < 4; r++) {
      ps[r] += __shfl_xor(ps[r], off);
      pd[r] += __shfl_xor(pd[r], off);
    }
  __syncthreads();
  if (l16 == 0) {
#pragma unroll
    for (int r = 0; r < 4; r++) {
      atomicAdd(&sp[quad * 4 + r], ps[r]);
      atomicAdd(&dp[quad * 4 + r], pd[r]);
    }
  }
  __syncthreads();
  if (t < 16) {
    srcv[rbase + t] = sp[t];
    dstv[rbase + t] = dp[t];
  }
}

// ---------------------------------------------------------------------------
// K2 (fused): whole-graph edge table staged in LDS -> 3-level scatter is pure
// LDS (divergent LDS gathers ~free vs serialized global gathers). Mt (bf16,
// unscaled exp) phase-overlays the Us region. 0.5/Z applied in GEMM epilogue.
// Phases: stage -> scatter(+softmax) -> exp/Mt -> att-fold -> GEMM. 4 barriers.
// ---------------------------------------------------------------------------
#define SM_MT    0                       // Mt: 16*1032*2 = 33024 B (Us inside: 32768 B)
#define SM_SB    33024                   // Sb: 16*257*4 = 16448 B
#define SM_N1    (33024 + 16448)         // n1: 512 B
#define SM_ATT   (SM_N1 + 512)           // attw: 512 B
#define SM_ZL    (SM_ATT + 512)          // zl: 1024 B
#define SM_ZR    (SM_ZL + 1024)          // Zr: 64 B
#define SM_TOT   (SM_ZR + 64)            // 51584 B -> 3 blocks/CU

__global__ __launch_bounds__(256) void k_fused(const int* __restrict__ uniq,
                                               const float* __restrict__ srcv,
                                               const float* __restrict__ dstv,
                                               const ushort* __restrict__ hT,
                                               float* __restrict__ out) {
  __shared__ __align__(16) unsigned char SM[SM_TOT];
  int* __restrict__ Us = (int*)SM;                       // phase 1 life
  ushort* __restrict__ Mt = (ushort*)SM;                 // phase 2 life
  unsigned* __restrict__ Sb = (unsigned*)(SM + SM_SB);
  int(*n1)[DG] = (int(*)[DG])(SM + SM_N1);
  float(*attw)[DG] = (float(*)[DG])(SM + SM_ATT);
  float(*zl)[16] = (float(*)[16])(SM + SM_ZL);
  float* Zr = (float*)(SM + SM_ZR);

  const int t = threadIdx.x, b = blockIdx.x;
  const int g = b >> 6, rbase = (b & 63) * BR;
  const int* __restrict__ Ug = uniq + (size_t)g * NN * DG;

  // --- stage: Us (32 KB coalesced), n1, zero Sb ---
  {
    const int4* Ug4 = (const int4*)Ug;
    int4* Us4 = (int4*)Us;
#pragma unroll
    for (int q = 0; q < 8; q++) Us4[t + 256 * q] = Ug4[t + 256 * q];
  }
  for (int i = t; i < BR * SBS; i += 256) Sb[i] = 0u;
  if (t < BR * DG) n1[t >> 3][t & 7] = Ug[(rbase + (t >> 3)) * DG + (t & 7)];
  __syncthreads();

  // --- scatter: 1024 items (r, s=e>>3, e&7), levels 1..3 fused per item ---
#pragma unroll
  for (int q = 0; q < 4; q++) {
    int idx = t + 256 * q;
    int r = idx >> 6, e = idx & 63;
    int j = n1[r][e >> 3];
    if (j >= 0) {
      if ((e & 7) == 0)  // level-1, once per (r,s)
        atomicAdd(&Sb[r * SBS + (j >> 2)], 1u << ((j & 3) * 8));
      int k = Us[j * DG + (e & 7)];
      if (k >= 0) {
        atomicAdd(&Sb[r * SBS + (k >> 2)], 1u << ((k & 3) * 8));  // level-2
        int4 m0 = *(const int4*)(Us + k * DG);
        int4 m1 = *(const int4*)(Us + k * DG + 4);
        int ll[8] = {m0.x, m0.y, m0.z, m0.w, m1.x, m1.y, m1.z, m1.w};
#pragma unroll
        for (int e2 = 0; e2 < 8; e2++)  // level-3
          if (ll[e2] >= 0) atomicAdd(&Sb[r * SBS + (ll[e2] >> 2)], 1u << ((ll[e2] & 3) * 8));
      }
    }
  }
  // att softmax (t<16, one row each; n1/srcv/dstv only — no Us dependency)
  if (t < BR) {
    int r = t;
    float si = srcv[g * NN + rbase + r];
    float ev[DG];
    float m = -1e30f;
#pragma unroll
    for (int s = 0; s < DG; s++) {
      int j = n1[r][s];
      if (j >= 0) {
        float x = si + dstv[g * NN + j];
        x = x > 0.f ? x : LALPHA * x;
        ev[s] = x;
        m = fmaxf(m, x);
      } else ev[s] = -1e30f;
    }
    float sm = 0.f;
#pragma unroll
    for (int s = 0; s < DG; s++) {
      float e = (n1[r][s] >= 0) ? __expf(ev[s] - m) : 0.f;
      ev[s] = e;
      sm += e;
    }
    float inv = 1.f / sm;
#pragma unroll
    for (int s = 0; s < DG; s++) attw[r][s] = ev[s] * inv;
  }
  __syncthreads();  // Us dead after this point; Mt may overwrite

  // --- single pass: Sb -> Mt (unscaled bf16 exp) + Z partials ---
  {
    const int r = t & 15, u = t >> 4;
    float zp = 0.f;
#pragma unroll
    for (int q = 0; q < 8; q++) {
      unsigned s0 = Sb[r * SBS + u * 16 + 2 * q];
      unsigned s1 = Sb[r * SBS + u * 16 + 2 * q + 1];
      float e0 = __expf((float)(s0 & 255u));
      float e1 = __expf((float)((s0 >> 8) & 255u));
      float e2 = __expf((float)((s0 >> 16) & 255u));
      float e3 = __expf((float)(s0 >> 24));
      float e4 = __expf((float)(s1 & 255u));
      float e5 = __expf((float)((s1 >> 8) & 255u));
      float e6 = __expf((float)((s1 >> 16) & 255u));
      float e7 = __expf((float)(s1 >> 24));
      zp += (e0 + e1) + (e2 + e3) + (e4 + e5) + (e6 + e7);
      union { uint4 v; ushort us[8]; } pk;
      pk.us[0] = f2bf(e0); pk.us[1] = f2bf(e1); pk.us[2] = f2bf(e2); pk.us[3] = f2bf(e3);
      pk.us[4] = f2bf(e4); pk.us[5] = f2bf(e5); pk.us[6] = f2bf(e6); pk.us[7] = f2bf(e7);
      *(uint4*)&Mt[r * MTS + u * 64 + q * 8] = pk.v;
    }
    zl[r][u] = zp;
  }
  __syncthreads();

  // --- att fold-in: Mt[j] += att*Z (epilogue scale 0.5/Z makes it 0.5*att) ---
  if (t < 128) {
    const int r = t >> 3, s = t & 7;
    float z = 0.f;
#pragma unroll
    for (int u = 0; u < 16; u++) z += zl[r][u];
    if (s == 0) Zr[r] = z;
    int j = n1[r][s];
    if (j >= 0) {
      int adr = r * MTS + j;
      Mt[adr] = f2bf(bf2f(Mt[adr]) + attw[r][s] * z);
    }
  }
  __syncthreads();

  // --- GEMM: wave w -> cols w*16..+16; A from LDS Mt, B direct from L2 hT ---
  const int w = t >> 6, lane = t & 63, quad = lane >> 4, l16 = lane & 15;
  const ushort* __restrict__ hrow = hT + ((size_t)g * FO + w * 16 + l16) * NN;
  f32x4 acc = {0.f, 0.f, 0.f, 0.f};
#pragma unroll 8
  for (int ks = 0; ks < NN; ks += 32) {
    bf16x8 af = *(const bf16x8*)&Mt[l16 * MTS + ks + quad * 8];
    bf16x8 bf = *(const bf16x8*)(hrow + ks + quad * 8);
    acc = __builtin_amdgcn_mfma_f32_16x16x32_bf16(af, bf, acc, 0, 0, 0);
  }
#pragma unroll
  for (int r = 0; r < 4; r++) {
    int rl = quad * 4 + r;
    float v = acc[r] * (0.5f / Zr[rl]);
    v = v > 0.f ? v : __expf(v) - 1.f;
    out[((size_t)(g * NN + rbase + rl)) * FO + w * 16 + l16] = v;
  }
}

// ---------------------------------------------------------------------------
extern "C" void kernel_launch(void* const* d_in, const int* in_sizes, int n_in,
                              void* d_out, int out_size, void* d_ws, size_t ws_size,
                              hipStream_t stream) {
  const float* atoms = (const float*)d_in[0];
  const int* edges = (const int*)d_in[1];
  const float* W = (const float*)d_in[2];
  const float* a = (const float*)d_in[3];
  float* out = (float*)d_out;

  const int nrows = in_sizes[0] / FI;   // B*N = 16384
  const int ngraph = nrows / NN;        // 16

  ushort* hT = (ushort*)d_ws;                                   // ngraph*FO*NN
  float* srcv = (float*)(hT + (size_t)ngraph * FO * NN);        // nrows
  float* dstv = srcv + nrows;                                   // nrows
  int* uniq = (int*)(dstv + nrows);                             // nrows*DG

  k_prep<<<nrows / 16, 256, 0, stream>>>(atoms, W, a, edges, uniq, hT, srcv, dstv);
  k_fused<<<ngraph * (NN / BR), 256, 0, stream>>>(uniq, srcv, dstv, hT, out);
}

// Round 7
// 98.009 us; speedup vs baseline: 1.0356x; 1.0356x over previous
//
#include <hip/hip_runtime.h>

#define NN 1024
#define DG 8
#define FO 64
#define FI 128
#define LALPHA 0.2f
#define BR 16        // output rows per fused block
#define SBS 257      // Sb row stride (u32 words), odd -> dense sweeps conflict-free
#define AHS 68       // attH row stride (floats), 4-aligned, bank-staggered

typedef __attribute__((ext_vector_type(8))) short bf16x8;
typedef __attribute__((ext_vector_type(4))) float f32x4;

static __device__ __forceinline__ unsigned short f2bf(float x) {
  union { float f; unsigned u; } v; v.f = x;
  unsigned r = v.u + 0x7FFFu + ((v.u >> 16) & 1u);  // round-to-nearest-even
  return (unsigned short)(r >> 16);
}
static __device__ __forceinline__ float bf2f(unsigned short h) {
  union { unsigned u; float f; } v; v.u = ((unsigned)h) << 16;
  return v.f;
}

// ---------------------------------------------------------------------------
// K1 (prep): dedupe edges (t<16) + h = atom@W via bf16 hi/lo MFMA, fragments
// straight from global. Outputs hT[g][f][node] (B-fragment layout), hN[row][f]
// (node-major, for the att@h correction), srcv/dstv fp32.
// ---------------------------------------------------------------------------
__global__ __launch_bounds__(256) void k_prep(const float* __restrict__ atoms,
                                              const float* __restrict__ W,
                                              const float* __restrict__ a,
                                              const int* __restrict__ edges,
                                              int* __restrict__ uniq,
                                              ushort* __restrict__ hT,
                                              ushort* __restrict__ hN,
                                              float* __restrict__ srcv,
                                              float* __restrict__ dstv) {
  __shared__ float sp[16], dp[16];
  const int t = threadIdx.x, b = blockIdx.x;
  const int g = b >> 6;
  const int rbase = b * 16;

  if (t < 16) {
    sp[t] = 0.f; dp[t] = 0.f;
    const int rr = rbase + t;
    int e[DG];
#pragma unroll
    for (int s = 0; s < DG; s++) e[s] = edges[rr * DG + s];
#pragma unroll
    for (int s = 0; s < DG; s++) {
      int v = e[s];
      bool dup = false;
#pragma unroll
      for (int q = 0; q < DG; q++)
        if (q < s && e[q] == v) dup = true;
      uniq[rr * DG + s] = dup ? -1 : v;
    }
  }

  const int w = t >> 6, lane = t & 63, quad = lane >> 4, l16 = lane & 15;
  const float* __restrict__ Ar = atoms + (size_t)(rbase + l16) * FI;
  const float* __restrict__ Wc = W + w * 16 + l16;
  f32x4 acc = {0.f, 0.f, 0.f, 0.f};
#pragma unroll
  for (int kc = 0; kc < 4; kc++) {
    const int k0 = kc * 32 + quad * 8;
    float4 a0 = *(const float4*)(Ar + k0);
    float4 a1 = *(const float4*)(Ar + k0 + 4);
    float av[8] = {a0.x, a0.y, a0.z, a0.w, a1.x, a1.y, a1.z, a1.w};
    float wv[8];
#pragma unroll
    for (int e = 0; e < 8; e++) wv[e] = Wc[(k0 + e) * FO];
    bf16x8 ahi, alo, bhi, blo;
#pragma unroll
    for (int e = 0; e < 8; e++) {
      ushort h = f2bf(av[e]);
      ahi[e] = (short)h;
      alo[e] = (short)f2bf(av[e] - bf2f(h));
      ushort g2 = f2bf(wv[e]);
      bhi[e] = (short)g2;
      blo[e] = (short)f2bf(wv[e] - bf2f(g2));
    }
    acc = __builtin_amdgcn_mfma_f32_16x16x32_bf16(ahi, bhi, acc, 0, 0, 0);
    acc = __builtin_amdgcn_mfma_f32_16x16x32_bf16(ahi, blo, acc, 0, 0, 0);
    acc = __builtin_amdgcn_mfma_f32_16x16x32_bf16(alo, bhi, acc, 0, 0, 0);
  }

  const int f = w * 16 + l16;
  const float as_ = a[f], ad_ = a[FO + f];
  float ps[4], pd[4];
#pragma unroll
  for (int r = 0; r < 4; r++) {
    float v = acc[r];
    int rb = rbase + quad * 4 + r;
    ushort hv = f2bf(v);
    hT[((size_t)g * FO + f) * NN + (rb & (NN - 1))] = hv;
    hN[(size_t)rb * FO + f] = hv;
    ps[r] = v * as_;
    pd[r] = v * ad_;
  }
#pragma unroll
  for (int off = 1; off < 16; off <<= 1)
#pragma unroll
    for (int r = 0; r < 4; r++) {
      ps[r] += __shfl_xor(ps[r], off);
      pd[r] += __shfl_xor(pd[r], off);
    }
  __syncthreads();
  if (l16 == 0) {
#pragma unroll
    for (int r = 0; r < 4; r++) {
      atomicAdd(&sp[quad * 4 + r], ps[r]);
      atomicAdd(&dp[quad * 4 + r], pd[r]);
    }
  }
  __syncthreads();
  if (t < 16) {
    srcv[rbase + t] = sp[t];
    dstv[rbase + t] = dp[t];
  }
}

// ---------------------------------------------------------------------------
// K2 (fused): NO materialized M. Phases (3 barriers):
//   1. zero Sb, stage n1
//   2. 3-level scatter into u8 byte-counters (LDS atomics) + att softmax
//   3. attH[r][f] = sum_s att_s * h[j_s][f]  (coalesced reads from hN)
//   4. GEMM: A-fragments generated on the fly (exp of Sb bytes -> bf16),
//      B direct from L2-resident hT; Z accumulated from fp32 exps in-loop;
//      epilogue: out = elu(0.5*attH + (0.5/Z)*acc).
// LDS ~22 KB -> 7 blocks/CU (28 waves/CU) — the occupancy fix.
// ---------------------------------------------------------------------------
__global__ __launch_bounds__(256, 6) void k_fused(const int* __restrict__ uniq,
                                                  const float* __restrict__ srcv,
                                                  const float* __restrict__ dstv,
                                                  const ushort* __restrict__ hT,
                                                  const ushort* __restrict__ hN,
                                                  float* __restrict__ out) {
  __shared__ unsigned Sb[BR * SBS];     // 16448 B byte counters
  __shared__ float attH[BR * AHS];      // 4352 B
  __shared__ int n1[BR][DG];
  __shared__ float attw[BR][DG];

  const int t = threadIdx.x, b = blockIdx.x;
  const int g = b >> 6, rbase = (b & 63) * BR;
  const int* __restrict__ Ug = uniq + (size_t)g * NN * DG;

  for (int i = t; i < BR * SBS; i += 256) Sb[i] = 0u;
  if (t < BR * DG) n1[t >> 3][t & 7] = Ug[(rbase + (t >> 3)) * DG + (t & 7)];
  __syncthreads();

  // --- scatter: 1024 items (r, s=e>>3, slot=e&7), levels 1..3 fused ---
#pragma unroll
  for (int q = 0; q < 4; q++) {
    int idx = t + 256 * q;
    int r = idx >> 6, e = idx & 63;
    int j = n1[r][e >> 3];
    if (j >= 0) {
      if ((e & 7) == 0)  // level-1, once per (r,s)
        atomicAdd(&Sb[r * SBS + (j >> 2)], 1u << ((j & 3) * 8));
      int k = Ug[j * DG + (e & 7)];
      if (k >= 0) {
        atomicAdd(&Sb[r * SBS + (k >> 2)], 1u << ((k & 3) * 8));  // level-2
        int4 m0 = *(const int4*)(Ug + k * DG);
        int4 m1 = *(const int4*)(Ug + k * DG + 4);
        int ll[8] = {m0.x, m0.y, m0.z, m0.w, m1.x, m1.y, m1.z, m1.w};
#pragma unroll
        for (int e2 = 0; e2 < 8; e2++)  // level-3
          if (ll[e2] >= 0) atomicAdd(&Sb[r * SBS + (ll[e2] >> 2)], 1u << ((ll[e2] & 3) * 8));
      }
    }
  }
  // att softmax (t<16, one row each)
  if (t < BR) {
    int r = t;
    float si = srcv[g * NN + rbase + r];
    float ev[DG];
    float m = -1e30f;
#pragma unroll
    for (int s = 0; s < DG; s++) {
      int j = n1[r][s];
      if (j >= 0) {
        float x = si + dstv[g * NN + j];
        x = x > 0.f ? x : LALPHA * x;
        ev[s] = x;
        m = fmaxf(m, x);
      } else ev[s] = -1e30f;
    }
    float sm = 0.f;
#pragma unroll
    for (int s = 0; s < DG; s++) {
      float e = (n1[r][s] >= 0) ? __expf(ev[s] - m) : 0.f;
      ev[s] = e;
      sm += e;
    }
    float inv = 1.f / sm;
#pragma unroll
    for (int s = 0; s < DG; s++) attw[r][s] = ev[s] * inv;
  }
  __syncthreads();

  // --- attH: thread (r = t>>4, f0 = (t&15)*4) -> 4 f-cols, coalesced hN reads ---
  {
    const int r = t >> 4, f0 = (t & 15) * 4;
    float a0 = 0.f, a1 = 0.f, a2 = 0.f, a3 = 0.f;
#pragma unroll
    for (int s = 0; s < DG; s++) {
      int j = n1[r][s];
      if (j >= 0) {
        float wgt = attw[r][s];
        uint2 hv = *(const uint2*)(hN + ((size_t)(g * NN + j)) * FO + f0);
        a0 += wgt * bf2f((ushort)(hv.x & 0xffffu));
        a1 += wgt * bf2f((ushort)(hv.x >> 16));
        a2 += wgt * bf2f((ushort)(hv.y & 0xffffu));
        a3 += wgt * bf2f((ushort)(hv.y >> 16));
      }
    }
    attH[r * AHS + f0] = a0;
    attH[r * AHS + f0 + 1] = a1;
    attH[r * AHS + f0 + 2] = a2;
    attH[r * AHS + f0 + 3] = a3;
  }
  __syncthreads();

  // --- GEMM with on-the-fly A-fragments + in-loop Z accumulation ---
  const int w = t >> 6, lane = t & 63, quad = lane >> 4, l16 = lane & 15;
  const ushort* __restrict__ hrow = hT + ((size_t)g * FO + w * 16 + l16) * NN;
  f32x4 acc = {0.f, 0.f, 0.f, 0.f};
  float zacc = 0.f;
#pragma unroll 8
  for (int ks = 0; ks < NN; ks += 32) {
    const int wd = l16 * SBS + (ks >> 2) + quad * 2;
    unsigned s0 = Sb[wd], s1 = Sb[wd + 1];
    float e0 = __expf((float)(s0 & 255u));
    float e1 = __expf((float)((s0 >> 8) & 255u));
    float e2 = __expf((float)((s0 >> 16) & 255u));
    float e3 = __expf((float)(s0 >> 24));
    float e4 = __expf((float)(s1 & 255u));
    float e5 = __expf((float)((s1 >> 8) & 255u));
    float e6 = __expf((float)((s1 >> 16) & 255u));
    float e7 = __expf((float)(s1 >> 24));
    zacc += (e0 + e1) + (e2 + e3) + (e4 + e5) + (e6 + e7);
    bf16x8 af;
    af[0] = (short)f2bf(e0); af[1] = (short)f2bf(e1);
    af[2] = (short)f2bf(e2); af[3] = (short)f2bf(e3);
    af[4] = (short)f2bf(e4); af[5] = (short)f2bf(e5);
    af[6] = (short)f2bf(e6); af[7] = (short)f2bf(e7);
    bf16x8 bf = *(const bf16x8*)(hrow + ks + quad * 8);
    acc = __builtin_amdgcn_mfma_f32_16x16x32_bf16(af, bf, acc, 0, 0, 0);
  }
  // Z[l16] = sum over all quads (each quad covered k%32 in [quad*8, quad*8+8))
  zacc += __shfl_xor(zacc, 16);
  zacc += __shfl_xor(zacc, 32);

#pragma unroll
  for (int r = 0; r < 4; r++) {
    const int row = quad * 4 + r;
    float Z = __shfl(zacc, row);             // lane 'row' (quad 0) has Z[row]
    float att = attH[row * AHS + w * 16 + l16];
    float v = 0.5f * att + acc[r] * (0.5f / Z);
    v = v > 0.f ? v : __expf(v) - 1.f;       // elu
    out[((size_t)(g * NN + rbase + row)) * FO + w * 16 + l16] = v;
  }
}

// ---------------------------------------------------------------------------
extern "C" void kernel_launch(void* const* d_in, const int* in_sizes, int n_in,
                              void* d_out, int out_size, void* d_ws, size_t ws_size,
                              hipStream_t stream) {
  const float* atoms = (const float*)d_in[0];
  const int* edges = (const int*)d_in[1];
  const float* W = (const float*)d_in[2];
  const float* a = (const float*)d_in[3];
  float* out = (float*)d_out;

  const int nrows = in_sizes[0] / FI;   // B*N = 16384
  const int ngraph = nrows / NN;        // 16

  ushort* hT = (ushort*)d_ws;                                   // ngraph*FO*NN
  ushort* hN = hT + (size_t)ngraph * FO * NN;                   // nrows*FO
  float* srcv = (float*)(hN + (size_t)nrows * FO);              // nrows
  float* dstv = srcv + nrows;                                   // nrows
  int* uniq = (int*)(dstv + nrows);                             // nrows*DG

  k_prep<<<nrows / 16, 256, 0, stream>>>(atoms, W, a, edges, uniq, hT, hN, srcv, dstv);
  k_fused<<<ngraph * (NN / BR), 256, 0, stream>>>(uniq, srcv, dstv, hT, hN, out);
}

// Round 8
// 96.092 us; speedup vs baseline: 1.0563x; 1.0199x over previous
//
#include <hip/hip_runtime.h>

#define NN 1024
#define DG 8
#define FO 64
#define FI 128
#define LALPHA 0.2f
#define BR 16        // output rows per fused block
#define SBS 257      // Sb row stride (u32 words)
#define RDS 68       // reduction row stride (floats)

typedef __attribute__((ext_vector_type(8))) short bf16x8;
typedef __attribute__((ext_vector_type(4))) float f32x4;

static __device__ __forceinline__ unsigned short f2bf(float x) {
  union { float f; unsigned u; } v; v.f = x;
  unsigned r = v.u + 0x7FFFu + ((v.u >> 16) & 1u);  // round-to-nearest-even
  return (unsigned short)(r >> 16);
}
static __device__ __forceinline__ float bf2f(unsigned short h) {
  union { unsigned u; float f; } v; v.u = ((unsigned)h) << 16;
  return v.f;
}

// ---------------------------------------------------------------------------
// K1 (prep): dedupe edges (t<16) + h = atom@W via bf16 hi/lo MFMA, fragments
// straight from global. Outputs hT[g][f][node], hN[row][f], srcv/dstv fp32.
// (unchanged from round 7)
// ---------------------------------------------------------------------------
__global__ __launch_bounds__(256) void k_prep(const float* __restrict__ atoms,
                                              const float* __restrict__ W,
                                              const float* __restrict__ a,
                                              const int* __restrict__ edges,
                                              int* __restrict__ uniq,
                                              ushort* __restrict__ hT,
                                              ushort* __restrict__ hN,
                                              float* __restrict__ srcv,
                                              float* __restrict__ dstv) {
  __shared__ float sp[16], dp[16];
  const int t = threadIdx.x, b = blockIdx.x;
  const int g = b >> 6;
  const int rbase = b * 16;

  if (t < 16) {
    sp[t] = 0.f; dp[t] = 0.f;
    const int rr = rbase + t;
    int e[DG];
#pragma unroll
    for (int s = 0; s < DG; s++) e[s] = edges[rr * DG + s];
#pragma unroll
    for (int s = 0; s < DG; s++) {
      int v = e[s];
      bool dup = false;
#pragma unroll
      for (int q = 0; q < DG; q++)
        if (q < s && e[q] == v) dup = true;
      uniq[rr * DG + s] = dup ? -1 : v;
    }
  }

  const int w = t >> 6, lane = t & 63, quad = lane >> 4, l16 = lane & 15;
  const float* __restrict__ Ar = atoms + (size_t)(rbase + l16) * FI;
  const float* __restrict__ Wc = W + w * 16 + l16;
  f32x4 acc = {0.f, 0.f, 0.f, 0.f};
#pragma unroll
  for (int kc = 0; kc < 4; kc++) {
    const int k0 = kc * 32 + quad * 8;
    float4 a0 = *(const float4*)(Ar + k0);
    float4 a1 = *(const float4*)(Ar + k0 + 4);
    float av[8] = {a0.x, a0.y, a0.z, a0.w, a1.x, a1.y, a1.z, a1.w};
    float wv[8];
#pragma unroll
    for (int e = 0; e < 8; e++) wv[e] = Wc[(k0 + e) * FO];
    bf16x8 ahi, alo, bhi, blo;
#pragma unroll
    for (int e = 0; e < 8; e++) {
      ushort h = f2bf(av[e]);
      ahi[e] = (short)h;
      alo[e] = (short)f2bf(av[e] - bf2f(h));
      ushort g2 = f2bf(wv[e]);
      bhi[e] = (short)g2;
      blo[e] = (short)f2bf(wv[e] - bf2f(g2));
    }
    acc = __builtin_amdgcn_mfma_f32_16x16x32_bf16(ahi, bhi, acc, 0, 0, 0);
    acc = __builtin_amdgcn_mfma_f32_16x16x32_bf16(ahi, blo, acc, 0, 0, 0);
    acc = __builtin_amdgcn_mfma_f32_16x16x32_bf16(alo, bhi, acc, 0, 0, 0);
  }

  const int f = w * 16 + l16;
  const float as_ = a[f], ad_ = a[FO + f];
  float ps[4], pd[4];
#pragma unroll
  for (int r = 0; r < 4; r++) {
    float v = acc[r];
    int rb = rbase + quad * 4 + r;
    ushort hv = f2bf(v);
    hT[((size_t)g * FO + f) * NN + (rb & (NN - 1))] = hv;
    hN[(size_t)rb * FO + f] = hv;
    ps[r] = v * as_;
    pd[r] = v * ad_;
  }
#pragma unroll
  for (int off = 1; off < 16; off <<= 1)
#pragma unroll
    for (int r = 0; r < 4; r++) {
      ps[r] += __shfl_xor(ps[r], off);
      pd[r] += __shfl_xor(pd[r], off);
    }
  __syncthreads();
  if (l16 == 0) {
#pragma unroll
    for (int r = 0; r < 4; r++) {
      atomicAdd(&sp[quad * 4 + r], ps[r]);
      atomicAdd(&dp[quad * 4 + r], pd[r]);
    }
  }
  __syncthreads();
  if (t < 16) {
    srcv[rbase + t] = sp[t];
    dstv[rbase + t] = dp[t];
  }
}

// ---------------------------------------------------------------------------
// K2 (fused): 3-level scatter -> u8 byte counters; GEMM is k-SPLIT across the
// 4 waves (each wave generates its A-fragments ONCE via an exp-LUT and does
// all 4 f-tiles), cross-wave reduce in LDS, fp32 epilogue with att + 0.5/Z.
// attH lives in registers (producer thread == consumer thread). 3 barriers.
// ---------------------------------------------------------------------------
__global__ __launch_bounds__(256, 4) void k_fused(const int* __restrict__ uniq,
                                                  const float* __restrict__ srcv,
                                                  const float* __restrict__ dstv,
                                                  const ushort* __restrict__ hT,
                                                  const ushort* __restrict__ hN,
                                                  float* __restrict__ out) {
  __shared__ unsigned Sb[BR * SBS];                 // 16448 B byte counters
  __shared__ __align__(16) float red[4][BR][RDS];   // 17408 B k-split partials
  __shared__ float zred[4][16];
  __shared__ int n1[BR][DG];
  __shared__ float attw[BR][DG];
  __shared__ float lutF[80];                        // exp(n) fp32, n=0..79
  __shared__ ushort lutB[80];                       // bf16(exp(n))

  const int t = threadIdx.x, b = blockIdx.x;
  const int g = b >> 6, rbase = (b & 63) * BR;
  const int* __restrict__ Ug = uniq + (size_t)g * NN * DG;

  for (int i = t; i < BR * SBS; i += 256) Sb[i] = 0u;
  if (t < BR * DG) n1[t >> 3][t & 7] = Ug[(rbase + (t >> 3)) * DG + (t & 7)];
  if (t >= 128 && t < 208) {
    int c = t - 128;
    float e = __expf((float)c);
    lutF[c] = e;
    lutB[c] = f2bf(e);
  }
  __syncthreads();

  // --- scatter: 1024 items (r, s=e>>3, slot=e&7), levels 1..3 fused ---
#pragma unroll
  for (int q = 0; q < 4; q++) {
    int idx = t + 256 * q;
    int r = idx >> 6, e = idx & 63;
    int j = n1[r][e >> 3];
    if (j >= 0) {
      if ((e & 7) == 0)  // level-1, once per (r,s)
        atomicAdd(&Sb[r * SBS + (j >> 2)], 1u << ((j & 3) * 8));
      int k = Ug[j * DG + (e & 7)];
      if (k >= 0) {
        atomicAdd(&Sb[r * SBS + (k >> 2)], 1u << ((k & 3) * 8));  // level-2
        int4 m0 = *(const int4*)(Ug + k * DG);
        int4 m1 = *(const int4*)(Ug + k * DG + 4);
        int ll[8] = {m0.x, m0.y, m0.z, m0.w, m1.x, m1.y, m1.z, m1.w};
#pragma unroll
        for (int e2 = 0; e2 < 8; e2++)  // level-3
          if (ll[e2] >= 0) atomicAdd(&Sb[r * SBS + (ll[e2] >> 2)], 1u << ((ll[e2] & 3) * 8));
      }
    }
  }
  // att softmax (t<16, one row each)
  if (t < BR) {
    int r = t;
    float si = srcv[g * NN + rbase + r];
    float ev[DG];
    float m = -1e30f;
#pragma unroll
    for (int s = 0; s < DG; s++) {
      int j = n1[r][s];
      if (j >= 0) {
        float x = si + dstv[g * NN + j];
        x = x > 0.f ? x : LALPHA * x;
        ev[s] = x;
        m = fmaxf(m, x);
      } else ev[s] = -1e30f;
    }
    float sm = 0.f;
#pragma unroll
    for (int s = 0; s < DG; s++) {
      float e = (n1[r][s] >= 0) ? __expf(ev[s] - m) : 0.f;
      ev[s] = e;
      sm += e;
    }
    float inv = 1.f / sm;
#pragma unroll
    for (int s = 0; s < DG; s++) attw[r][s] = ev[s] * inv;
  }
  __syncthreads();

  // --- attH in REGISTERS: thread t -> (row rr_, cols f0_..f0_+4) ---
  const int rr_ = t >> 4, f0_ = (t & 15) * 4;
  float ah0 = 0.f, ah1 = 0.f, ah2 = 0.f, ah3 = 0.f;
#pragma unroll
  for (int s = 0; s < DG; s++) {
    int j = n1[rr_][s];
    if (j >= 0) {
      float wgt = attw[rr_][s];
      uint2 hv = *(const uint2*)(hN + ((size_t)(g * NN + j)) * FO + f0_);
      ah0 += wgt * bf2f((ushort)(hv.x & 0xffffu));
      ah1 += wgt * bf2f((ushort)(hv.x >> 16));
      ah2 += wgt * bf2f((ushort)(hv.y & 0xffffu));
      ah3 += wgt * bf2f((ushort)(hv.y >> 16));
    }
  }

  // --- k-split GEMM: wave v covers nodes [v*256, v*256+256) ---
  const int v = t >> 6, lane = t & 63, quad = lane >> 4, l16 = lane & 15;
  const int k0 = v * 256;
  const ushort* __restrict__ hb = hT + ((size_t)g * FO) * NN;
  f32x4 acc[4] = {{0.f, 0.f, 0.f, 0.f}, {0.f, 0.f, 0.f, 0.f},
                  {0.f, 0.f, 0.f, 0.f}, {0.f, 0.f, 0.f, 0.f}};
  float zacc = 0.f;
#pragma unroll
  for (int ks = 0; ks < 256; ks += 32) {
    const int wd = l16 * SBS + ((k0 + ks) >> 2) + quad * 2;
    unsigned s0 = Sb[wd], s1 = Sb[wd + 1];
    const int c0 = s0 & 255u, c1 = (s0 >> 8) & 255u, c2 = (s0 >> 16) & 255u, c3 = s0 >> 24;
    const int c4 = s1 & 255u, c5 = (s1 >> 8) & 255u, c6 = (s1 >> 16) & 255u, c7 = s1 >> 24;
    bf16x8 af;
    af[0] = (short)lutB[c0]; af[1] = (short)lutB[c1];
    af[2] = (short)lutB[c2]; af[3] = (short)lutB[c3];
    af[4] = (short)lutB[c4]; af[5] = (short)lutB[c5];
    af[6] = (short)lutB[c6]; af[7] = (short)lutB[c7];
    zacc += (lutF[c0] + lutF[c1]) + (lutF[c2] + lutF[c3]) +
            (lutF[c4] + lutF[c5]) + (lutF[c6] + lutF[c7]);
    const ushort* hp = hb + (size_t)l16 * NN + k0 + ks + quad * 8;
#pragma unroll
    for (int ct = 0; ct < 4; ct++) {
      bf16x8 bf = *(const bf16x8*)(hp + (size_t)(ct * 16) * NN);
      acc[ct] = __builtin_amdgcn_mfma_f32_16x16x32_bf16(af, bf, acc[ct], 0, 0, 0);
    }
  }
  zacc += __shfl_xor(zacc, 16);
  zacc += __shfl_xor(zacc, 32);
  if (lane < 16) zred[v][lane] = zacc;
#pragma unroll
  for (int ct = 0; ct < 4; ct++)
#pragma unroll
    for (int r = 0; r < 4; r++)
      red[v][quad * 4 + r][ct * 16 + l16] = acc[ct][r];
  __syncthreads();

  // --- epilogue: thread t -> (row rr_, cols f0_..f0_+4), coalesced float4 ---
  const float Z = zred[0][rr_] + zred[1][rr_] + zred[2][rr_] + zred[3][rr_];
  const float hz = 0.5f / Z;
  f32x4 s = *(const f32x4*)&red[0][rr_][f0_];
  f32x4 s1v = *(const f32x4*)&red[1][rr_][f0_];
  f32x4 s2v = *(const f32x4*)&red[2][rr_][f0_];
  f32x4 s3v = *(const f32x4*)&red[3][rr_][f0_];
  float o0 = 0.5f * ah0 + (s[0] + s1v[0] + s2v[0] + s3v[0]) * hz;
  float o1 = 0.5f * ah1 + (s[1] + s1v[1] + s2v[1] + s3v[1]) * hz;
  float o2 = 0.5f * ah2 + (s[2] + s1v[2] + s2v[2] + s3v[2]) * hz;
  float o3 = 0.5f * ah3 + (s[3] + s1v[3] + s2v[3] + s3v[3]) * hz;
  o0 = o0 > 0.f ? o0 : __expf(o0) - 1.f;
  o1 = o1 > 0.f ? o1 : __expf(o1) - 1.f;
  o2 = o2 > 0.f ? o2 : __expf(o2) - 1.f;
  o3 = o3 > 0.f ? o3 : __expf(o3) - 1.f;
  *(float4*)(out + ((size_t)(g * NN + rbase + rr_)) * FO + f0_) =
      make_float4(o0, o1, o2, o3);
}

// ---------------------------------------------------------------------------
extern "C" void kernel_launch(void* const* d_in, const int* in_sizes, int n_in,
                              void* d_out, int out_size, void* d_ws, size_t ws_size,
                              hipStream_t stream) {
  const float* atoms = (const float*)d_in[0];
  const int* edges = (const int*)d_in[1];
  const float* W = (const float*)d_in[2];
  const float* a = (const float*)d_in[3];
  float* out = (float*)d_out;

  const int nrows = in_sizes[0] / FI;   // B*N = 16384
  const int ngraph = nrows / NN;        // 16

  ushort* hT = (ushort*)d_ws;                                   // ngraph*FO*NN
  ushort* hN = hT + (size_t)ngraph * FO * NN;                   // nrows*FO
  float* srcv = (float*)(hN + (size_t)nrows * FO);              // nrows
  float* dstv = srcv + nrows;                                   // nrows
  int* uniq = (int*)(dstv + nrows);                             // nrows*DG

  k_prep<<<nrows / 16, 256, 0, stream>>>(atoms, W, a, edges, uniq, hT, hN, srcv, dstv);
  k_fused<<<ngraph * (NN / BR), 256, 0, stream>>>(uniq, srcv, dstv, hT, hN, out);
}